// Round 17
// baseline (1838.816 us; speedup 1.0000x reference)
//
#include <hip/hip_runtime.h>

typedef short bf8 __attribute__((ext_vector_type(8)));
typedef float f32x4 __attribute__((ext_vector_type(4)));
typedef uint u32x4 __attribute__((ext_vector_type(4)));

static constexpr int BB = 256;   // batch
static constexpr int TT = 128;   // time
static constexpr int II = 512;   // input features
static constexpr int HH = 1024;  // hidden
static constexpr int OO = 512;   // fc out features
static constexpr int G4 = 4096;  // 4*H

static constexpr size_t OUT_H = (size_t)BB * OO;
static constexpr size_t OUT_C = OUT_H + (size_t)BB * HH;
static constexpr size_t HBUF  = (size_t)BB * HH;   // one h buffer (elems)

__device__ __forceinline__ float bf2f(ushort u) {
    unsigned v = ((unsigned)u) << 16;
    return __builtin_bit_cast(float, v);
}
__device__ __forceinline__ ushort f2bf(float f) {
    unsigned x = __builtin_bit_cast(unsigned, f);
    x = x + 0x7FFFu + ((x >> 16) & 1u);
    return (ushort)(x >> 16);
}
__device__ __forceinline__ float sigf(float x) { return 1.0f / (1.0f + __expf(-x)); }
__device__ __forceinline__ float tanhf_(float x) { return 2.0f * sigf(2.0f * x) - 1.0f; }

// ---- write-through / bypass ops (R4-validated protocol) ----
__device__ __forceinline__ void st_wt_short(const ushort* p, uint v) {
    asm volatile("global_store_short %0, %1, off sc0 sc1" :: "v"(p), "v"(v) : "memory");
}
__device__ __forceinline__ void st_wt_b128(const ushort* p, u32x4 v) {
    asm volatile("global_store_dwordx4 %0, %1, off sc0 sc1" :: "v"(p), "v"(v) : "memory");
}
__device__ __forceinline__ void ld_bp_ushort_issue(uint& dst, const ushort* p) {
    asm volatile("global_load_ushort %0, %1, off sc0 sc1" : "=v"(dst) : "v"(p) : "memory");
}
__device__ __forceinline__ void ld_bp_b128_issue(u32x4& dst, const ushort* p) {
    asm volatile("global_load_dwordx4 %0, %1, off sc0 sc1" : "=v"(dst) : "v"(p) : "memory");
}
__device__ __forceinline__ void wait_vm0() {
    asm volatile("s_waitcnt vmcnt(0)" ::: "memory");
    __builtin_amdgcn_sched_barrier(0);
}
#define WAITVM(N) do { asm volatile("s_waitcnt vmcnt(" #N ")" ::: "memory"); \
                       __builtin_amdgcn_sched_barrier(0); } while (0)

// ---- light group barrier, 128 blocks: wave 0 polls 2 flags/lane ----
__device__ __forceinline__ void lightbar128(int* slots, int bg, int gen) {
    asm volatile("s_waitcnt vmcnt(0) lgkmcnt(0)" ::: "memory");
    __builtin_amdgcn_sched_barrier(0);
    __syncthreads();
    int tid = threadIdx.x;
    if (tid == 0)
        asm volatile("global_store_dword %0, %1, off sc0 sc1" :: "v"(slots + bg * 32), "v"(gen) : "memory");
    if (tid < 64) {
        const int* p1 = slots + tid * 32;
        const int* p2 = slots + (tid + 64) * 32;
        int v1, v2;
        for (;;) {
            asm volatile("global_load_dword %0, %2, off sc0 sc1\n\t"
                         "global_load_dword %1, %3, off sc0 sc1\n\t"
                         "s_waitcnt vmcnt(0)"
                         : "=v"(v1), "=v"(v2) : "v"(p1), "v"(p2) : "memory");
            if (__all(v1 >= gen && v2 >= gen)) break;
            __builtin_amdgcn_s_sleep(1);
        }
    }
    __syncthreads();
}

// flags: 4 groups x 128 slots x 32 pad = 16384 ints
__global__ void k_init(int* flags) {
    int i = blockIdx.x * 256 + threadIdx.x;
    if (i < 16384) flags[i] = 0;
}

__global__ void k_cast(const float* __restrict__ src, ushort* __restrict__ dst, int n4) {
    int i = blockIdx.x * blockDim.x + threadIdx.x;
    int stride = gridDim.x * blockDim.x;
    for (; i < n4; i += stride) {
        float4 v = ((const float4*)src)[i];
        ushort4 o;
        o.x = f2bf(v.x); o.y = f2bf(v.y); o.z = f2bf(v.z); o.w = f2bf(v.w);
        ((ushort4*)dst)[i] = o;
    }
}

// NEW permutation for P=128: p = j*32 + n*16 + c  (j 0..127, n 0..1, c 0..15)
// gate = (n<<1)|(c>>3), hc = j*8 + (c&7), orig = gate*1024 + hc
__global__ void k_prep_w(const float* __restrict__ w, ushort* __restrict__ wp,
                         const float* __restrict__ bi, const float* __restrict__ bh,
                         float* __restrict__ bp, int Kdim) {
    int p = blockIdx.x;
    int jj = p >> 5, n = (p >> 4) & 1, c = p & 15;
    int gate = (n << 1) | (c >> 3);
    int orig = gate * HH + (jj << 3) + (c & 7);
    const float* src = w + (size_t)orig * Kdim;
    ushort* dst = wp + (size_t)p * Kdim;
    for (int k = threadIdx.x; k < Kdim; k += 256) dst[k] = f2bf(src[k]);
    if (threadIdx.x == 0 && bp) bp[p] = bi[orig] + bh[orig];
}

// ---- persistent kernel: 512 blocks (2 per CU), 4 groups x 128 blocks.
// bid<256: groups 0/1 (rows [0,128)); bid>=256: groups 2/3 (rows [128,256)).
// CU c hosts bid c and bid c+256 -> two INDEPENDENT recurrences share the CU so the
// hardware scheduler overlaps their UC load pipelines (the measured per-step wall).
// Block = 64 rows x 32 permuted gate cols; W_hh slice 64 KiB in LDS.
__global__ __launch_bounds__(256, 2) void k_main(
    const float* __restrict__ x, const ushort* __restrict__ wpih,
    const float* __restrict__ bp, ushort* __restrict__ pre,
    const ushort* __restrict__ wphh, ushort* __restrict__ hbf,
    float* __restrict__ dout, int* flags, int SEG) {
    __shared__ ushort wl[32 * 1024];  // 64 KiB: W slice, [ko][32 cols][32 kk] swizzled
    __shared__ ushort Al[64 * 32];    // 4 KiB: phase-A A stage / h pack (1 KB)
    __shared__ ushort Bl[128 * 32];   // 8 KiB: phase-A B stage

    int tid = threadIdx.x;
    int bid = blockIdx.x;
    int g = ((bid >> 8) << 1) | ((bid >> 7) & 1);   // 0..3
    int j = bid & 127;                               // 0..127
    int row0 = g << 6;
    int* slots = flags + g * 4096;
    int gen = 0;
    int nseg = TT / SEG;

    int w = tid >> 6, l = tid & 63;
    int l15 = l & 15, kg = l >> 4;
    int wbase = ((l15 << 6) + (kg << 4)) ^ ((l15 & 7) << 4);

    // load W_hh slice (32 permuted rows) into LDS; zero our h0 slice (64 rows x 8 hcols)
    {
        const ushort* wsrc = wphh + (size_t)(j << 5) * HH;
        for (int s = 0; s < 16; ++s) {
            int cidx = (s << 8) + tid;     // 0..4095 16B chunks
            int c = cidx >> 7;             // 0..31 col
            int kc = cidx & 127;           // 16B unit along K
            uint4 v = *(const uint4*)(wsrc + (size_t)c * HH + (kc << 3));
            int byte = ((kc >> 2) << 11) + ((((c << 6) + ((kc & 3) << 4))) ^ ((c & 7) << 4));
            *(uint4*)((char*)wl + byte) = v;
        }
        if (tid < 64) {
            u32x4 z = {0, 0, 0, 0};
            st_wt_b128(hbf + (size_t)(row0 + tid) * HH + (j << 3), z);
        }
    }

    // phase A addressing (tile = 64 rows x 128 permuted cols, 2x2 waves)
    int wm = w >> 1, wn = w & 1;
    int r0 = tid >> 2, kk = tid & 3;
    int sbyteA = ((r0 << 6) + (kk << 4)) ^ ((r0 & 7) << 4);
    int sbyteB1 = sbyteA + 4096;

    // phase B addressing
    const ushort* hbase = hbf + (size_t)(row0 + (w << 4) + l15) * HH + (kg << 3);
    int drow = row0 + (w << 4) + (kg << 2);
    int hcol = (j << 3) + (l15 & 7);
    bool hi = (l15 & 8) != 0;
    const ushort* pbase = pre + (size_t)drow * G4 + (j << 5) + l15;
    float creg[4] = {0.f, 0.f, 0.f, 0.f};

    for (int sg = 0; sg < nseg; ++sg) {
        int t0 = sg * SEG;
        // ===== phase A: pre[t0..t0+SEG) for our 64 rows; 128 blocks split the tiles =====
        int ntiles = SEG << 5;
        for (int q = j; q < ntiles; q += 128) {
            int trel = q >> 5;
            int t = t0 + trel;
            int n0 = (q & 31) << 7;
            const float* xa = x + ((size_t)(row0 + r0) * TT + t) * II + (kk << 3);
            const ushort* gb0 = wpih + (size_t)(n0 + r0) * II + (kk << 3);
            const ushort* gb1 = gb0 + (size_t)64 * II;
            f32x4 acc[2][4];
#pragma unroll
            for (int mi = 0; mi < 2; ++mi)
#pragma unroll
                for (int ni = 0; ni < 4; ++ni) acc[mi][ni] = f32x4{0.f, 0.f, 0.f, 0.f};
            float4 a0 = *(const float4*)xa;
            float4 a1 = *(const float4*)(xa + 4);
            uint4 b0v = *(const uint4*)gb0;
            uint4 b1v = *(const uint4*)gb1;
            for (int ko = 0; ko < 16; ++ko) {
                union { ushort us[8]; uint4 v; } pa;
                pa.us[0] = f2bf(a0.x); pa.us[1] = f2bf(a0.y); pa.us[2] = f2bf(a0.z); pa.us[3] = f2bf(a0.w);
                pa.us[4] = f2bf(a1.x); pa.us[5] = f2bf(a1.y); pa.us[6] = f2bf(a1.z); pa.us[7] = f2bf(a1.w);
                __syncthreads();
                *(uint4*)((char*)Al + sbyteA) = pa.v;
                *(uint4*)((char*)Bl + sbyteA) = b0v;
                *(uint4*)((char*)Bl + sbyteB1) = b1v;
                __syncthreads();
                if (ko < 15) {
                    int k = (ko + 1) << 5;
                    a0 = *(const float4*)(xa + k);
                    a1 = *(const float4*)(xa + k + 4);
                    b0v = *(const uint4*)(gb0 + k);
                    b1v = *(const uint4*)(gb1 + k);
                }
                bf8 af[2], bv[4];
#pragma unroll
                for (int mi = 0; mi < 2; ++mi)
                    af[mi] = *(const bf8*)((char*)Al + wm * 2048 + mi * 1024 + wbase);
#pragma unroll
                for (int ni = 0; ni < 4; ++ni)
                    bv[ni] = *(const bf8*)((char*)Bl + wn * 4096 + ni * 1024 + wbase);
#pragma unroll
                for (int mi = 0; mi < 2; ++mi)
#pragma unroll
                    for (int ni = 0; ni < 4; ++ni)
                        acc[mi][ni] = __builtin_amdgcn_mfma_f32_16x16x32_bf16(af[mi], bv[ni], acc[mi][ni], 0, 0, 0);
            }
#pragma unroll
            for (int ni = 0; ni < 4; ++ni) {
                int col = n0 + wn * 64 + ni * 16 + l15;
                float bias = bp[col];
#pragma unroll
                for (int mi = 0; mi < 2; ++mi) {
                    int arow = row0 + wm * 32 + mi * 16 + (kg << 2);
#pragma unroll
                    for (int r = 0; r < 4; ++r)
                        st_wt_short(pre + ((size_t)trel * BB + arow + r) * G4 + col,
                                    (uint)f2bf(acc[mi][ni][r] + bias));
                }
            }
        }
        gen++; lightbar128(slots, j, gen);  // pre chunk + (sg==0) h0 zeros visible

        // ===== phase B: SEG recurrent steps =====
        uint prn[8];
#pragma unroll
        for (int n = 0; n < 2; ++n)
#pragma unroll
            for (int r = 0; r < 4; ++r)
                ld_bp_ushort_issue(prn[n * 4 + r], pbase + (size_t)r * G4 + (n << 4));
        wait_vm0();

        for (int trel = 0; trel < SEG; ++trel) {
            int t = t0 + trel;
            const ushort* hr = hbase + (size_t)(t & 1) * HBUF;
            u32x4 xv[8], yv[8];

#define ISSUE8(B, C) \
            _Pragma("unroll") \
            for (int u = 0; u < 8; ++u) ld_bp_b128_issue(B[u], hr + (((C) * 8 + u) << 5));
#define CONSUME8(B, C) \
            _Pragma("unroll") \
            for (int u = 0; u < 8; ++u) { \
                int ko = (C) * 8 + u; \
                bf8 a = __builtin_bit_cast(bf8, B[u]); \
                _Pragma("unroll") \
                for (int n = 0; n < 2; ++n) { \
                    bf8 b = *(const bf8*)((char*)wl + ko * 2048 + n * 1024 + wbase); \
                    acc[n] = __builtin_amdgcn_mfma_f32_16x16x32_bf16(a, b, acc[n], 0, 0, 0); \
                } \
            }

            f32x4 acc[2];
            ISSUE8(xv, 0)              // 8 outstanding
            ISSUE8(yv, 1)              // 16
#pragma unroll
            for (int n = 0; n < 2; ++n)
#pragma unroll
                for (int r = 0; r < 4; ++r) acc[n][r] = bf2f((ushort)prn[n * 4 + r]);
            WAITVM(8);                 // c0 done
            CONSUME8(xv, 0)
            ISSUE8(xv, 2)              // 16
            WAITVM(8);                 // c1 done
            CONSUME8(yv, 1)
            ISSUE8(yv, 3)              // 16
            WAITVM(8);                 // c2 done
            CONSUME8(xv, 2)
            {   // prefetch next step's pre slice (8 UC loads; drains at step-end wait_vm0)
                int nrel = (trel + 1 < SEG) ? trel + 1 : 0;
                const ushort* pnn = pre + ((size_t)nrel * BB + drow) * G4 + (j << 5) + l15;
#pragma unroll
                for (int n = 0; n < 2; ++n)
#pragma unroll
                    for (int r = 0; r < 4; ++r)
                        ld_bp_ushort_issue(prn[n * 4 + r], pnn + (size_t)r * G4 + (n << 4));
            }                          // 8 (c3) + 8 (prn) = 16 outstanding
            WAITVM(8);                 // c3 done
            CONSUME8(yv, 3)
#undef ISSUE8
#undef CONSUME8

            // gates: lanes (l15, l15^8) hold {i,g} / {f,o}; one xor-8 shuffle pairs them
            bool last = (t == TT - 1);
#pragma unroll
            for (int r = 0; r < 4; ++r) {
                float a0 = acc[0][r], a1 = acc[1][r];
                float x0 = __shfl_xor(a0, 8);
                float x1 = __shfl_xor(a1, 8);
                float ig = hi ? x0 : a0;
                float fg = hi ? a0 : x0;
                float gg = hi ? x1 : a1;
                float og = hi ? a1 : x1;
                float c = sigf(fg) * creg[r] + sigf(ig) * tanhf_(gg);
                creg[r] = c;
                float h = sigf(og) * tanhf_(c);
                if (!hi) {
                    Al[((w << 4) + (kg << 2) + r) * 8 + (l15 & 7)] = f2bf(h);
                    if (last) {
                        dout[OUT_H + (size_t)(drow + r) * HH + hcol] = h;
                        dout[OUT_C + (size_t)(drow + r) * HH + hcol] = c;
                    }
                }
            }
            __syncthreads();
            if (tid < 64) {   // 64 coalesced b128 stores: row tid, 8 cols
                u32x4 v = *(const u32x4*)(Al + (tid << 3));
                st_wt_b128(hbf + (size_t)((t & 1) ^ 1) * HBUF
                           + (size_t)(row0 + tid) * HH + (j << 3), v);
            }
            gen++; lightbar128(slots, j, gen);   // drains h stores + prn
        }
    }
}

// ---- FC: out = h_final @ W_fc^T + b_fc (h_128 lands in h buffer 0) ----
__global__ __launch_bounds__(256) void k_fc(const ushort* __restrict__ hlast,
                                            const ushort* __restrict__ wfc,
                                            const float* __restrict__ bfc,
                                            float* __restrict__ out) {
    int tid = threadIdx.x;
    int b0 = (blockIdx.x >> 3) << 6;
    int n0 = (blockIdx.x & 7) << 6;
    int w = tid >> 6, l = tid & 63;
    int l15 = l & 15, kg = l >> 4;
    const ushort* ha = hlast + (size_t)(b0 + (w << 4) + l15) * HH + (kg << 3);
    f32x4 acc[4];
#pragma unroll
    for (int ni = 0; ni < 4; ++ni) acc[ni] = f32x4{0.f, 0.f, 0.f, 0.f};
    for (int ko = 0; ko < 32; ++ko) {
        bf8 a = *(const bf8*)(ha + (ko << 5));
#pragma unroll
        for (int ni = 0; ni < 4; ++ni) {
            bf8 b = *(const bf8*)(wfc + (size_t)(n0 + ni * 16 + l15) * HH + (ko << 5) + (kg << 3));
            acc[ni] = __builtin_amdgcn_mfma_f32_16x16x32_bf16(a, b, acc[ni], 0, 0, 0);
        }
    }
    int drow = b0 + (w << 4) + (kg << 2);
#pragma unroll
    for (int ni = 0; ni < 4; ++ni) {
        int col = n0 + ni * 16 + l15;
        float bias = bfc[col];
#pragma unroll
        for (int r = 0; r < 4; ++r)
            out[(size_t)(drow + r) * OO + col] = acc[ni][r] + bias;
    }
}

extern "C" void kernel_launch(void* const* d_in, const int* in_sizes, int n_in,
                              void* d_out, int out_size, void* d_ws, size_t ws_size,
                              hipStream_t stream) {
    const float* x   = (const float*)d_in[0];
    const float* Wih = (const float*)d_in[1];
    const float* Whh = (const float*)d_in[2];
    const float* bih = (const float*)d_in[3];
    const float* bhh = (const float*)d_in[4];
    const float* Wfc = (const float*)d_in[5];
    const float* bfc = (const float*)d_in[6];
    float* out = (float*)d_out;

    char* ws = (char*)d_ws;
    size_t off = 0;
    ushort* wpih = (ushort*)(ws + off); off += (size_t)G4 * II * 2;       // 4.2 MB
    ushort* wphh = (ushort*)(ws + off); off += (size_t)G4 * HH * 2;       // 8.4 MB
    ushort* wfcb = (ushort*)(ws + off); off += (size_t)OO * HH * 2;       // 1.0 MB
    float*  bp   = (float*)(ws + off);  off += (size_t)G4 * 4;            // 16 KB
    int*    flags= (int*)(ws + off);    off += 16384 * 4;                 // 64 KB
    ushort* hbf  = (ushort*)(ws + off); off += (size_t)2 * BB * HH * 2;   // 1.0 MB ping-pong
    size_t fixed = off;
    int SEG = 16;
    while (SEG > 1 && fixed + (size_t)SEG * BB * G4 * 2 > ws_size) SEG >>= 1;
    ushort* pre = (ushort*)(ws + fixed);   // SEG * 2.1 MB (<= 33.6 MB)

    k_init<<<64, 256, 0, stream>>>(flags);
    k_cast<<<256, 256, 0, stream>>>(Wfc, wfcb, OO * HH / 4);
    k_prep_w<<<G4, 256, 0, stream>>>(Wih, wpih, bih, bhh, bp, II);
    k_prep_w<<<G4, 256, 0, stream>>>(Whh, wphh, nullptr, nullptr, nullptr, HH);
    k_main<<<512, 256, 0, stream>>>(x, wpih, bp, pre, wphh, hbf, out, flags, SEG);
    k_fc<<<32, 256, 0, stream>>>(hbf, wfcb, bfc, out);
}

// Round 18
// 1529.843 us; speedup vs baseline: 1.2020x; 1.2020x over previous
//
#include <hip/hip_runtime.h>

typedef short bf8 __attribute__((ext_vector_type(8)));
typedef float f32x4 __attribute__((ext_vector_type(4)));
typedef uint u32x4 __attribute__((ext_vector_type(4)));

static constexpr int BB = 256;   // batch
static constexpr int TT = 128;   // time
static constexpr int II = 512;   // input features
static constexpr int HH = 1024;  // hidden
static constexpr int OO = 512;   // fc out features
static constexpr int G4 = 4096;  // 4*H

static constexpr size_t OUT_H = (size_t)BB * OO;
static constexpr size_t OUT_C = OUT_H + (size_t)BB * HH;
static constexpr size_t HBUF  = (size_t)BB * HH;   // one h buffer (elems)

__device__ __forceinline__ float bf2f(ushort u) {
    unsigned v = ((unsigned)u) << 16;
    return __builtin_bit_cast(float, v);
}
__device__ __forceinline__ ushort f2bf(float f) {
    unsigned x = __builtin_bit_cast(unsigned, f);
    x = x + 0x7FFFu + ((x >> 16) & 1u);
    return (ushort)(x >> 16);
}
__device__ __forceinline__ float sigf(float x) { return 1.0f / (1.0f + __expf(-x)); }
__device__ __forceinline__ float tanhf_(float x) { return 2.0f * sigf(2.0f * x) - 1.0f; }

// ---- write-through / bypass ops (R4-validated) ----
__device__ __forceinline__ void st_wt_short(const ushort* p, uint v) {
    asm volatile("global_store_short %0, %1, off sc0 sc1" :: "v"(p), "v"(v) : "memory");
}
__device__ __forceinline__ void st_wt_b64(const ushort* p, uint2 v) {
    asm volatile("global_store_dwordx2 %0, %1, off sc0 sc1" :: "v"(p), "v"(v) : "memory");
}
__device__ __forceinline__ void ld_bp_ushort_issue(uint& dst, const ushort* p) {
    asm volatile("global_load_ushort %0, %1, off sc0 sc1" : "=v"(dst) : "v"(p) : "memory");
}
__device__ __forceinline__ void ld_bp_b128_issue(u32x4& dst, const ushort* p) {
    asm volatile("global_load_dwordx4 %0, %1, off sc0 sc1" : "=v"(dst) : "v"(p) : "memory");
}
__device__ __forceinline__ void wait_vm0() {
    asm volatile("s_waitcnt vmcnt(0)" ::: "memory");
    __builtin_amdgcn_sched_barrier(0);
}
#define WAITVM(N) do { asm volatile("s_waitcnt vmcnt(" #N ")" ::: "memory"); \
                       __builtin_amdgcn_sched_barrier(0); } while (0)

// ---- light group barrier: 64 blocks, store+poll, zero cache fences ----
__device__ __forceinline__ void lightbar(int* slots, int bg, int gen) {
    asm volatile("s_waitcnt vmcnt(0) lgkmcnt(0)" ::: "memory");
    __builtin_amdgcn_sched_barrier(0);
    __syncthreads();
    int tid = threadIdx.x;
    if (tid == 0)
        asm volatile("global_store_dword %0, %1, off sc0 sc1" :: "v"(slots + bg * 32), "v"(gen) : "memory");
    if (tid < 64) {
        const int* sp = slots + tid * 32;
        int v;
        do {
            asm volatile("global_load_dword %0, %1, off sc0 sc1\n\ts_waitcnt vmcnt(0)"
                         : "=v"(v) : "v"(sp) : "memory");
            if (v >= gen) break;
            __builtin_amdgcn_s_sleep(1);
        } while (true);
    }
    __syncthreads();
}

// flags: 4 groups x 64 slots x 32 pad
__global__ void k_init(int* flags) {
    int i = blockIdx.x * 256 + threadIdx.x;
    if (i < 8192) flags[i] = 0;
}

__global__ void k_cast(const float* __restrict__ src, ushort* __restrict__ dst, int n4) {
    int i = blockIdx.x * blockDim.x + threadIdx.x;
    int stride = gridDim.x * blockDim.x;
    for (; i < n4; i += stride) {
        float4 v = ((const float4*)src)[i];
        ushort4 o;
        o.x = f2bf(v.x); o.y = f2bf(v.y); o.z = f2bf(v.z); o.w = f2bf(v.w);
        ((ushort4*)dst)[i] = o;
    }
}

// permuted index p = j*64 + gate*16 + hc  ->  original row = gate*1024 + j*16 + hc
__global__ void k_prep_w(const float* __restrict__ w, ushort* __restrict__ wp,
                         const float* __restrict__ bi, const float* __restrict__ bh,
                         float* __restrict__ bp, int Kdim) {
    int p = blockIdx.x;
    int orig = ((p >> 4) & 3) * HH + ((p >> 6) << 4) + (p & 15);
    const float* src = w + (size_t)orig * Kdim;
    ushort* dst = wp + (size_t)p * Kdim;
    for (int k = threadIdx.x; k < Kdim; k += 256) dst[k] = f2bf(src[k]);
    if (threadIdx.x == 0 && bp) bp[p] = bi[orig] + bh[orig];
}

// ---- persistent phased kernel: 4 groups x 64 blocks; block = 64 rows x 64 permuted cols ----
// R10 measured-best configuration, restored verbatim.
template <int HMODE>
__global__ __launch_bounds__(256) void k_main(
    const float* __restrict__ x, const ushort* __restrict__ wpih,
    const float* __restrict__ bp, ushort* __restrict__ pre,
    const ushort* __restrict__ wphh, ushort* __restrict__ hbf,
    float* __restrict__ dout, int* flags, int SEG) {
    __shared__ ushort wl[32 * 2048];  // W_hh slice (swizzled), 128 KiB
    __shared__ ushort Al[64 * 32];    // phase A stage
    __shared__ ushort Bl[128 * 32];

    int tid = threadIdx.x;
    int bid = blockIdx.x;
    int g = bid >> 6, j = bid & 63;
    int row0 = g << 6;
    int* slots = flags + g * 2048;
    int gen = 0;
    int nseg = TT / SEG;

    int w = tid >> 6, l = tid & 63;
    int l15 = l & 15, kg = l >> 4;
    int wbase = ((l15 << 6) + (kg << 4)) ^ ((l15 & 7) << 4);

    // load W_hh slice into LDS (swizzled); zero our slice of h buffer 0 (write-through)
    {
        const ushort* wsrc = wphh + (size_t)(j << 6) * HH;
        for (int s = 0; s < 32; ++s) {
            int cidx = (s << 8) + tid;
            int c = cidx >> 7;
            int kc = cidx & 127;
            uint4 v = *(const uint4*)(wsrc + (size_t)c * HH + (kc << 3));
            int byte = ((kc >> 2) << 12) + ((((c << 6) + ((kc & 3) << 4))) ^ ((c & 7) << 4));
            *(uint4*)((char*)wl + byte) = v;
        }
        int r = tid >> 2, hc = (tid & 3) << 2;
        uint2 z; z.x = 0; z.y = 0;
        st_wt_b64(hbf + (size_t)(row0 + r) * HH + (j << 4) + hc, z);
    }

    // phase A addressing
    int wm = w >> 1, wn = w & 1;
    int r0 = tid >> 2, kk = tid & 3;
    int sbyteA = ((r0 << 6) + (kk << 4)) ^ ((r0 & 7) << 4);
    int sbyteB1 = sbyteA + 4096;

    // phase B addressing
    const ushort* hbase = hbf + (size_t)(row0 + (w << 4) + l15) * HH + (kg << 3);
    int drow = row0 + (w << 4) + (kg << 2);
    int hcol = (j << 4) + l15;
    ushort* hobase = hbf + (size_t)drow * HH + hcol;
    const ushort* pbase = pre + (size_t)drow * G4 + (j << 6) + l15;
    float creg[4] = {0.f, 0.f, 0.f, 0.f};

    for (int sg = 0; sg < nseg; ++sg) {
        int t0 = sg * SEG;
        // ===== phase A: pre[t0..t0+SEG) for our 64 batch rows (tiles 64x128, K=512) =====
        int ntiles = SEG << 5;
        for (int q = j; q < ntiles; q += 64) {
            int trel = q >> 5;
            int t = t0 + trel;
            int n0 = (q & 31) << 7;
            const float* xa = x + ((size_t)(row0 + r0) * TT + t) * II + (kk << 3);
            const ushort* gb0 = wpih + (size_t)(n0 + r0) * II + (kk << 3);
            const ushort* gb1 = gb0 + (size_t)64 * II;
            f32x4 acc[2][4];
#pragma unroll
            for (int mi = 0; mi < 2; ++mi)
#pragma unroll
                for (int ni = 0; ni < 4; ++ni) acc[mi][ni] = f32x4{0.f, 0.f, 0.f, 0.f};
            float4 a0 = *(const float4*)xa;
            float4 a1 = *(const float4*)(xa + 4);
            uint4 b0v = *(const uint4*)gb0;
            uint4 b1v = *(const uint4*)gb1;
            for (int ko = 0; ko < 16; ++ko) {
                union { ushort us[8]; uint4 v; } pa;
                pa.us[0] = f2bf(a0.x); pa.us[1] = f2bf(a0.y); pa.us[2] = f2bf(a0.z); pa.us[3] = f2bf(a0.w);
                pa.us[4] = f2bf(a1.x); pa.us[5] = f2bf(a1.y); pa.us[6] = f2bf(a1.z); pa.us[7] = f2bf(a1.w);
                __syncthreads();
                *(uint4*)((char*)Al + sbyteA) = pa.v;
                *(uint4*)((char*)Bl + sbyteA) = b0v;
                *(uint4*)((char*)Bl + sbyteB1) = b1v;
                __syncthreads();
                if (ko < 15) {
                    int k = (ko + 1) << 5;
                    a0 = *(const float4*)(xa + k);
                    a1 = *(const float4*)(xa + k + 4);
                    b0v = *(const uint4*)(gb0 + k);
                    b1v = *(const uint4*)(gb1 + k);
                }
                bf8 af[2], bv[4];
#pragma unroll
                for (int mi = 0; mi < 2; ++mi)
                    af[mi] = *(const bf8*)((char*)Al + wm * 2048 + mi * 1024 + wbase);
#pragma unroll
                for (int ni = 0; ni < 4; ++ni)
                    bv[ni] = *(const bf8*)((char*)Bl + wn * 4096 + ni * 1024 + wbase);
#pragma unroll
                for (int mi = 0; mi < 2; ++mi)
#pragma unroll
                    for (int ni = 0; ni < 4; ++ni)
                        acc[mi][ni] = __builtin_amdgcn_mfma_f32_16x16x32_bf16(af[mi], bv[ni], acc[mi][ni], 0, 0, 0);
            }
#pragma unroll
            for (int ni = 0; ni < 4; ++ni) {
                int col = n0 + wn * 64 + ni * 16 + l15;
                float bias = bp[col];
#pragma unroll
                for (int mi = 0; mi < 2; ++mi) {
                    int arow = row0 + wm * 32 + mi * 16 + (kg << 2);
#pragma unroll
                    for (int r = 0; r < 4; ++r)
                        st_wt_short(pre + ((size_t)trel * BB + arow + r) * G4 + col,
                                    (uint)f2bf(acc[mi][ni][r] + bias));
                }
            }
        }
        gen++; lightbar(slots, j, gen);  // pre chunk + (sg==0) h0 zeros visible group-wide

        // ===== phase B: SEG recurrent steps =====
        uint prn[16];
#pragma unroll
        for (int ni = 0; ni < 4; ++ni)
#pragma unroll
            for (int r = 0; r < 4; ++r)
                ld_bp_ushort_issue(prn[ni * 4 + r], pbase + (size_t)r * G4 + (ni << 4));
        wait_vm0();

        for (int trel = 0; trel < SEG; ++trel) {
            int t = t0 + trel;
            int rb = t & 1;
            int wb = (t & 1) ^ 1;
            const ushort* hr = hbase + (size_t)rb * HBUF;
            u32x4 xv[8], yv[8];

#define ISSUE8(B, C) \
            _Pragma("unroll") \
            for (int u = 0; u < 8; ++u) ld_bp_b128_issue(B[u], hr + (((C) * 8 + u) << 5));
#define CONSUME8(B, C) \
            _Pragma("unroll") \
            for (int u = 0; u < 8; ++u) { \
                int ko = (C) * 8 + u; \
                bf8 a = __builtin_bit_cast(bf8, B[u]); \
                _Pragma("unroll") \
                for (int ni = 0; ni < 4; ++ni) { \
                    bf8 b = *(const bf8*)((char*)wl + ko * 4096 + ni * 1024 + wbase); \
                    acc[ni] = __builtin_amdgcn_mfma_f32_16x16x32_bf16(a, b, acc[ni], 0, 0, 0); \
                } \
            }

            f32x4 acc[4];
            ISSUE8(xv, 0)              // 8 outstanding
            ISSUE8(yv, 1)              // 16
#pragma unroll
            for (int ni = 0; ni < 4; ++ni)
#pragma unroll
                for (int r = 0; r < 4; ++r) acc[ni][r] = bf2f((ushort)prn[ni * 4 + r]);
            WAITVM(8);                 // c0 done
            CONSUME8(xv, 0)
            ISSUE8(xv, 2)              // 16
            WAITVM(8);                 // c1 done
            CONSUME8(yv, 1)
            ISSUE8(yv, 3)              // 16
            WAITVM(8);                 // c2 done
            CONSUME8(xv, 2)
            {   // prefetch next step's pre slice (bypass; drains at lightbar)
                int nrel = (trel + 1 < SEG) ? trel + 1 : 0;
                const ushort* pnn = pre + ((size_t)nrel * BB + drow) * G4 + (j << 6) + l15;
#pragma unroll
                for (int ni = 0; ni < 4; ++ni)
#pragma unroll
                    for (int r = 0; r < 4; ++r)
                        ld_bp_ushort_issue(prn[ni * 4 + r], pnn + (size_t)r * G4 + (ni << 4));
            }                          // 8 (c3) + 16 (prn) = 24 outstanding
            WAITVM(16);                // c3 done (prn drains at lightbar)
            CONSUME8(yv, 3)
#undef ISSUE8
#undef CONSUME8

            ushort* ho = hobase + (size_t)wb * HBUF;
            bool last = (t == TT - 1);
#pragma unroll
            for (int r = 0; r < 4; ++r) {
                float ig = sigf(acc[0][r]);
                float fg = sigf(acc[1][r]);
                float gg = tanhf_(acc[2][r]);
                float og = sigf(acc[3][r]);
                float c = fg * creg[r] + ig * gg;
                creg[r] = c;
                float h = og * tanhf_(c);
                st_wt_short(ho + (size_t)r * HH, (uint)f2bf(h));
                if (last) {
                    dout[OUT_H + (size_t)(drow + r) * HH + hcol] = h;
                    dout[OUT_C + (size_t)(drow + r) * HH + hcol] = c;
                }
            }
            gen++; lightbar(slots, j, gen);
        }
    }
}

// ---- FC: out = h_final @ W_fc^T + b_fc (h_128 lands in h buffer 0) ----
__global__ __launch_bounds__(256) void k_fc(const ushort* __restrict__ hlast,
                                            const ushort* __restrict__ wfc,
                                            const float* __restrict__ bfc,
                                            float* __restrict__ out) {
    int tid = threadIdx.x;
    int b0 = (blockIdx.x >> 3) << 6;
    int n0 = (blockIdx.x & 7) << 6;
    int w = tid >> 6, l = tid & 63;
    int l15 = l & 15, kg = l >> 4;
    const ushort* ha = hlast + (size_t)(b0 + (w << 4) + l15) * HH + (kg << 3);
    f32x4 acc[4];
#pragma unroll
    for (int ni = 0; ni < 4; ++ni) acc[ni] = f32x4{0.f, 0.f, 0.f, 0.f};
    for (int ko = 0; ko < 32; ++ko) {
        bf8 a = *(const bf8*)(ha + (ko << 5));
#pragma unroll
        for (int ni = 0; ni < 4; ++ni) {
            bf8 b = *(const bf8*)(wfc + (size_t)(n0 + ni * 16 + l15) * HH + (ko << 5) + (kg << 3));
            acc[ni] = __builtin_amdgcn_mfma_f32_16x16x32_bf16(a, b, acc[ni], 0, 0, 0);
        }
    }
    int drow = b0 + (w << 4) + (kg << 2);
#pragma unroll
    for (int ni = 0; ni < 4; ++ni) {
        int col = n0 + ni * 16 + l15;
        float bias = bfc[col];
#pragma unroll
        for (int r = 0; r < 4; ++r)
            out[(size_t)(drow + r) * OO + col] = acc[ni][r] + bias;
    }
}

extern "C" void kernel_launch(void* const* d_in, const int* in_sizes, int n_in,
                              void* d_out, int out_size, void* d_ws, size_t ws_size,
                              hipStream_t stream) {
    const float* x   = (const float*)d_in[0];
    const float* Wih = (const float*)d_in[1];
    const float* Whh = (const float*)d_in[2];
    const float* bih = (const float*)d_in[3];
    const float* bhh = (const float*)d_in[4];
    const float* Wfc = (const float*)d_in[5];
    const float* bfc = (const float*)d_in[6];
    float* out = (float*)d_out;

    char* ws = (char*)d_ws;
    size_t off = 0;
    ushort* wpih = (ushort*)(ws + off); off += (size_t)G4 * II * 2;       // 4.2 MB
    ushort* wphh = (ushort*)(ws + off); off += (size_t)G4 * HH * 2;       // 8.4 MB
    ushort* wfcb = (ushort*)(ws + off); off += (size_t)OO * HH * 2;       // 1.0 MB
    float*  bp   = (float*)(ws + off);  off += (size_t)G4 * 4;            // 16 KB
    int*    flags= (int*)(ws + off);    off += 8192 * 4;                  // 32 KB
    ushort* hbf  = (ushort*)(ws + off); off += (size_t)2 * BB * HH * 2;   // 1.0 MB ping-pong
    size_t fixed = off;
    int SEG = 16;
    while (SEG > 1 && fixed + (size_t)SEG * BB * G4 * 2 > ws_size) SEG >>= 1;
    ushort* pre = (ushort*)(ws + fixed);   // SEG * 2.1 MB (<= 33.6 MB)

    k_init<<<32, 256, 0, stream>>>(flags);
    k_cast<<<256, 256, 0, stream>>>(Wfc, wfcb, OO * HH / 4);
    k_prep_w<<<G4, 256, 0, stream>>>(Wih, wpih, bih, bhh, bp, II);
    k_prep_w<<<G4, 256, 0, stream>>>(Whh, wphh, nullptr, nullptr, nullptr, HH);
    k_main<1><<<256, 256, 0, stream>>>(x, wpih, bp, pre, wphh, hbf, out, flags, SEG);
    k_fc<<<32, 256, 0, stream>>>(hbf, wfcb, bfc, out);
}